// Round 10
// baseline (131.877 us; speedup 1.0000x reference)
//
#include <hip/hip_runtime.h>

#define DEV __device__ __forceinline__

// Fixed-size value-semantics vector (pure SSA after inlining).
template <int N> struct V { float v[N == 0 ? 1 : N]; };

// General Batcher odd-even merge, by value (verified absmax=0.0 on HW, r2/3/5/8/9).
template <int M, int N>
DEV V<M + N> mrg(V<M> a, V<N> b) {
    V<M + N> o;
    if constexpr (M == 0) {
#pragma unroll
        for (int i = 0; i < N; ++i) o.v[i] = b.v[i];
    } else if constexpr (N == 0) {
#pragma unroll
        for (int i = 0; i < M; ++i) o.v[i] = a.v[i];
    } else if constexpr (M == 1 && N == 1) {
        o.v[0] = fminf(a.v[0], b.v[0]);
        o.v[1] = fmaxf(a.v[0], b.v[0]);
    } else if constexpr ((M & 1) && (N & 1)) {
        constexpr int AE = (M + 1) / 2, AO = M / 2, BE = (N + 1) / 2, BO = N / 2;
        V<AE> ae; V<AO> ao; V<BE> be; V<BO> bo;
#pragma unroll
        for (int i = 0; i < AE; ++i) ae.v[i] = a.v[2 * i];
#pragma unroll
        for (int i = 0; i < AO; ++i) ao.v[i] = a.v[2 * i + 1];
#pragma unroll
        for (int i = 0; i < BE; ++i) be.v[i] = b.v[2 * i];
#pragma unroll
        for (int i = 0; i < BO; ++i) bo.v[i] = b.v[2 * i + 1];
        V<AE + BO> E = mrg<AE, BO>(ae, bo);
        V<AO + BE> O = mrg<AO, BE>(ao, be);
        constexpr int P = AE + BO;
#pragma unroll
        for (int i = 0; i < P; ++i) {
            o.v[2 * i] = fminf(E.v[i], O.v[i]);
            o.v[2 * i + 1] = fmaxf(E.v[i], O.v[i]);
        }
    } else {
        constexpr int AE = (M + 1) / 2, AO = M / 2, BE = (N + 1) / 2, BO = N / 2;
        V<AE> ae; V<AO> ao; V<BE> be; V<BO> bo;
#pragma unroll
        for (int i = 0; i < AE; ++i) ae.v[i] = a.v[2 * i];
#pragma unroll
        for (int i = 0; i < AO; ++i) ao.v[i] = a.v[2 * i + 1];
#pragma unroll
        for (int i = 0; i < BE; ++i) be.v[i] = b.v[2 * i];
#pragma unroll
        for (int i = 0; i < BO; ++i) bo.v[i] = b.v[2 * i + 1];
        V<AE + BE> E = mrg<AE, BE>(ae, be);
        V<AO + BO> O = mrg<AO, BO>(ao, bo);
        constexpr int CEn = AE + BE, COn = AO + BO;
        o.v[0] = E.v[0];
#pragma unroll
        for (int i = 0; i < COn; ++i) {
            if (i + 1 < CEn) {
                o.v[2 * i + 1] = fminf(O.v[i], E.v[i + 1]);
                o.v[2 * i + 2] = fmaxf(O.v[i], E.v[i + 1]);
            } else {
                o.v[2 * i + 1] = O.v[i];
            }
        }
    }
    return o;
}

DEV void ce(float& a, float& b) {
    float lo = fminf(a, b);
    b = fmaxf(a, b);
    a = lo;
}

// sort7 = sort3 (min3/med3/max3) + sort4 (5 CE) + merge(3,4). (verified r5/r8/r9)
DEV V<7> sort7(V<7> x) {
    float a = x.v[0], b = x.v[1], c = x.v[2];
    V<3> s3;
    s3.v[0] = fminf(fminf(a, b), c);
    s3.v[1] = __builtin_amdgcn_fmed3f(a, b, c);
    s3.v[2] = fmaxf(fmaxf(a, b), c);
    ce(x.v[3], x.v[4]); ce(x.v[5], x.v[6]);
    ce(x.v[3], x.v[5]); ce(x.v[4], x.v[6]); ce(x.v[4], x.v[5]);
    V<4> s4;
    s4.v[0] = x.v[3]; s4.v[1] = x.v[4]; s4.v[2] = x.v[5]; s4.v[3] = x.v[6];
    return mrg<3, 4>(s3, s4);
}

// rank-24 (0-indexed) of union(A[0..41], c[0..6]): min over i+j==25 of
// max(A[i-1], c[j-1]); j<=7 -> 8 terms, only A[17..24] consumed (DCE prunes
// the rest of the 42-merge). (verified r9, absmax=0.0)
DEV float sel8(const V<42>& A, const V<7>& c) {
    float t0 = A.v[24];                    // i=25, j=0
    float t1 = fmaxf(A.v[23], c.v[0]);
    float t2 = fmaxf(A.v[22], c.v[1]);
    float t3 = fmaxf(A.v[21], c.v[2]);
    float t4 = fmaxf(A.v[20], c.v[3]);
    float t5 = fmaxf(A.v[19], c.v[4]);
    float t6 = fmaxf(A.v[18], c.v[5]);
    float t7 = fmaxf(A.v[17], c.v[6]);
    return fminf(fminf(fminf(t0, t1), fminf(t2, t3)),
                 fminf(fminf(t4, t5), fminf(t6, t7)));
}

static constexpr int W = 512, H = 512, PLANE = W * H;

// R9 kernel with ONE change: waves_per_eu (1,3) -> (1,7).
// r9 evidence: network fits 68 VGPRs naturally (no pressure at 170 budget);
// occupancy 29.5% was purely the max=3 cap; VALUBusy tracks occupancy
// linearly (17.5%->54, 29.5%->51, 40%->64) => latency-bound, need waves.
// Budget 512/7 = 73 >= 68 actual => no spill; ceiling 7 waves/SIMD.
__global__ __launch_bounds__(256) __attribute__((amdgpu_waves_per_eu(1, 7)))
void median7_hardtanh_kernel(const float* __restrict__ in,
                             float* __restrict__ out) {
    // XCD-aware bijective swizzle: 6144 blocks = 8 XCDs x 768 contiguous.
    int bid = (int)blockIdx.x;
    int swz = (bid & 7) * 768 + (bid >> 3);

    int local = (int)threadIdx.x;
    int tx = local & 127;          // 128 threads per row
    int ry = local >> 7;           // 2 rows per block
    int r = swz * 2 + ry;          // global row = plane*512 + y
    int y = r & (H - 1);
    int p = r >> 9;
    const float* img = in + (size_t)p * PLANE;
    int x0 = tx * 4;

    int rows[7];
#pragma unroll
    for (int i = 0; i < 7; ++i) {
        int t = y + i - 3;
        t = (t < 0) ? -t : t;
        t = (t > H - 1) ? 2 * (H - 1) - t : t;
        rows[i] = t << 9;
    }

    V<7> c0, c1, c2, c3, c4, c5, c6, c7, c8, c9;
    if (x0 >= 4 && x0 <= W - 8) {
        // interior: 3 aligned float4 loads per row cover cols x0-4 .. x0+7
#pragma unroll
        for (int i = 0; i < 7; ++i) {
            const float* rp = img + rows[i] + x0;
            float4 L = *reinterpret_cast<const float4*>(rp - 4);
            float4 C = *reinterpret_cast<const float4*>(rp);
            float4 R = *reinterpret_cast<const float4*>(rp + 4);
            c0.v[i] = L.y; c1.v[i] = L.z; c2.v[i] = L.w;
            c3.v[i] = C.x; c4.v[i] = C.y; c5.v[i] = C.z; c6.v[i] = C.w;
            c7.v[i] = R.x; c8.v[i] = R.y; c9.v[i] = R.z;
        }
    } else {
        // border threads (tx==0 or tx==127): branch-free reflected columns
        int cols[10];
#pragma unroll
        for (int j = 0; j < 10; ++j) {
            int u = x0 + j - 3;
            u = (u < 0) ? -u : u;
            u = (u > W - 1) ? 2 * (W - 1) - u : u;
            cols[j] = u;
        }
#pragma unroll
        for (int i = 0; i < 7; ++i) {
            const float* rp = img + rows[i];
            c0.v[i] = rp[cols[0]]; c1.v[i] = rp[cols[1]]; c2.v[i] = rp[cols[2]];
            c3.v[i] = rp[cols[3]]; c4.v[i] = rp[cols[4]]; c5.v[i] = rp[cols[5]];
            c6.v[i] = rp[cols[6]]; c7.v[i] = rp[cols[7]]; c8.v[i] = rp[cols[8]];
            c9.v[i] = rp[cols[9]];
        }
    }

    c0 = sort7(c0); c1 = sort7(c1); c2 = sort7(c2); c3 = sort7(c3);
    c4 = sort7(c4); c5 = sort7(c5); c6 = sort7(c6); c7 = sort7(c7);
    c8 = sort7(c8); c9 = sort7(c9);

    V<28> Q = mrg<14, 14>(mrg<7, 7>(c3, c4), mrg<7, 7>(c5, c6));

    V<42> QP12 = mrg<28, 14>(Q, mrg<7, 7>(c1, c2));
    float m0 = sel8(QP12, c0);
    float m1 = sel8(QP12, c7);

    V<42> QP78 = mrg<28, 14>(Q, mrg<7, 7>(c7, c8));
    float m2 = sel8(QP78, c2);
    float m3 = sel8(QP78, c9);

    float4 o;
    o.x = fminf(fmaxf(m0, 0.0f), 1.0f);
    o.y = fminf(fmaxf(m1, 0.0f), 1.0f);
    o.z = fminf(fmaxf(m2, 0.0f), 1.0f);
    o.w = fminf(fmaxf(m3, 0.0f), 1.0f);
    *reinterpret_cast<float4*>(out + (size_t)r * W + x0) = o;
}

extern "C" void kernel_launch(void* const* d_in, const int* in_sizes, int n_in,
                              void* d_out, int out_size, void* d_ws, size_t ws_size,
                              hipStream_t stream) {
    const float* x = (const float*)d_in[0];
    float* outp = (float*)d_out;
    int rows_total = out_size / W;      // 12288
    int blocks = rows_total / 2;        // 6144
    median7_hardtanh_kernel<<<blocks, 256, 0, stream>>>(x, outp);
}

// Round 11
// 110.110 us; speedup vs baseline: 1.1977x; 1.1977x over previous
//
#include <hip/hip_runtime.h>

#define DEV __device__ __forceinline__

// Fixed-size value-semantics vector (pure SSA after inlining).
template <int N> struct V { float v[N == 0 ? 1 : N]; };

// General Batcher odd-even merge, by value (verified absmax=0.0 on HW, r2-r10).
template <int M, int N>
DEV V<M + N> mrg(V<M> a, V<N> b) {
    V<M + N> o;
    if constexpr (M == 0) {
#pragma unroll
        for (int i = 0; i < N; ++i) o.v[i] = b.v[i];
    } else if constexpr (N == 0) {
#pragma unroll
        for (int i = 0; i < M; ++i) o.v[i] = a.v[i];
    } else if constexpr (M == 1 && N == 1) {
        o.v[0] = fminf(a.v[0], b.v[0]);
        o.v[1] = fmaxf(a.v[0], b.v[0]);
    } else if constexpr ((M & 1) && (N & 1)) {
        constexpr int AE = (M + 1) / 2, AO = M / 2, BE = (N + 1) / 2, BO = N / 2;
        V<AE> ae; V<AO> ao; V<BE> be; V<BO> bo;
#pragma unroll
        for (int i = 0; i < AE; ++i) ae.v[i] = a.v[2 * i];
#pragma unroll
        for (int i = 0; i < AO; ++i) ao.v[i] = a.v[2 * i + 1];
#pragma unroll
        for (int i = 0; i < BE; ++i) be.v[i] = b.v[2 * i];
#pragma unroll
        for (int i = 0; i < BO; ++i) bo.v[i] = b.v[2 * i + 1];
        V<AE + BO> E = mrg<AE, BO>(ae, bo);
        V<AO + BE> O = mrg<AO, BE>(ao, be);
        constexpr int P = AE + BO;
#pragma unroll
        for (int i = 0; i < P; ++i) {
            o.v[2 * i] = fminf(E.v[i], O.v[i]);
            o.v[2 * i + 1] = fmaxf(E.v[i], O.v[i]);
        }
    } else {
        constexpr int AE = (M + 1) / 2, AO = M / 2, BE = (N + 1) / 2, BO = N / 2;
        V<AE> ae; V<AO> ao; V<BE> be; V<BO> bo;
#pragma unroll
        for (int i = 0; i < AE; ++i) ae.v[i] = a.v[2 * i];
#pragma unroll
        for (int i = 0; i < AO; ++i) ao.v[i] = a.v[2 * i + 1];
#pragma unroll
        for (int i = 0; i < BE; ++i) be.v[i] = b.v[2 * i];
#pragma unroll
        for (int i = 0; i < BO; ++i) bo.v[i] = b.v[2 * i + 1];
        V<AE + BE> E = mrg<AE, BE>(ae, be);
        V<AO + BO> O = mrg<AO, BO>(ao, bo);
        constexpr int CEn = AE + BE, COn = AO + BO;
        o.v[0] = E.v[0];
#pragma unroll
        for (int i = 0; i < COn; ++i) {
            if (i + 1 < CEn) {
                o.v[2 * i + 1] = fminf(O.v[i], E.v[i + 1]);
                o.v[2 * i + 2] = fmaxf(O.v[i], E.v[i + 1]);
            } else {
                o.v[2 * i + 1] = O.v[i];
            }
        }
    }
    return o;
}

DEV void ce(float& a, float& b) {
    float lo = fminf(a, b);
    b = fmaxf(a, b);
    a = lo;
}

// sort7 = sort3 (min3/med3/max3) + sort4 (5 CE) + merge(3,4). (verified r5-r10)
DEV V<7> sort7(V<7> x) {
    float a = x.v[0], b = x.v[1], c = x.v[2];
    V<3> s3;
    s3.v[0] = fminf(fminf(a, b), c);
    s3.v[1] = __builtin_amdgcn_fmed3f(a, b, c);
    s3.v[2] = fmaxf(fmaxf(a, b), c);
    ce(x.v[3], x.v[4]); ce(x.v[5], x.v[6]);
    ce(x.v[3], x.v[5]); ce(x.v[4], x.v[6]); ce(x.v[4], x.v[5]);
    V<4> s4;
    s4.v[0] = x.v[3]; s4.v[1] = x.v[4]; s4.v[2] = x.v[5]; s4.v[3] = x.v[6];
    return mrg<3, 4>(s3, s4);
}

// rank-24 (0-indexed) of union(A[0..41], c[0..6]): min over i+j==25 of
// max(A[i-1], c[j-1]); only A[17..24] consumed (DCE prunes). (verified r9/r10)
DEV float sel8(const V<42>& A, const V<7>& c) {
    float t0 = A.v[24];
    float t1 = fmaxf(A.v[23], c.v[0]);
    float t2 = fmaxf(A.v[22], c.v[1]);
    float t3 = fmaxf(A.v[21], c.v[2]);
    float t4 = fmaxf(A.v[20], c.v[3]);
    float t5 = fmaxf(A.v[19], c.v[4]);
    float t6 = fmaxf(A.v[18], c.v[5]);
    float t7 = fmaxf(A.v[17], c.v[6]);
    return fminf(fminf(fminf(t0, t1), fminf(t2, t3)),
                 fminf(fminf(t4, t5), fminf(t6, t7)));
}

static constexpr int W = 512, H = 512, PLANE = W * H;

// R10 kernel with ONE mechanism changed: border handling.
// (a) chunk = (tx+1)&127 puts BOTH border chunks (0,127) in the same wave ->
//     waves 0,2 of each block skip the border branch via execz entirely
//     (previously all 4 waves contained a border lane and paid the full
//     divergent path: ~70 serial scalar loads before the vmcnt drain).
// (b) border path rebuilt: only x0==0 and x0==508 exist, and their reflected
//     windows are compile-time permutations of 2 aligned float4/row ->
//     14 vector loads + static wiring, zero index math, no scalar-load tail.
__global__ __launch_bounds__(256) __attribute__((amdgpu_waves_per_eu(1, 7)))
void median7_hardtanh_kernel(const float* __restrict__ in,
                             float* __restrict__ out) {
    // XCD-aware bijective swizzle: 6144 blocks = 8 XCDs x 768 contiguous.
    int bid = (int)blockIdx.x;
    int swz = (bid & 7) * 768 + (bid >> 3);

    int local = (int)threadIdx.x;
    int tx = local & 127;            // 128 threads per row
    int ry = local >> 7;             // 2 rows per block
    int chunk = (tx + 1) & 127;      // border chunks 0 and 127 share a wave
    int r = swz * 2 + ry;            // global row = plane*512 + y
    int y = r & (H - 1);
    int p = r >> 9;
    const float* img = in + (size_t)p * PLANE;
    int x0 = chunk * 4;

    int rows[7];
#pragma unroll
    for (int i = 0; i < 7; ++i) {
        int t = y + i - 3;
        t = (t < 0) ? -t : t;
        t = (t > H - 1) ? 2 * (H - 1) - t : t;
        rows[i] = t << 9;
    }

    V<7> c0, c1, c2, c3, c4, c5, c6, c7, c8, c9;
    if (x0 >= 4 && x0 <= W - 8) {
        // interior: 3 aligned float4 loads per row cover cols x0-4 .. x0+7
#pragma unroll
        for (int i = 0; i < 7; ++i) {
            const float* rp = img + rows[i] + x0;
            float4 L = *reinterpret_cast<const float4*>(rp - 4);
            float4 C = *reinterpret_cast<const float4*>(rp);
            float4 R = *reinterpret_cast<const float4*>(rp + 4);
            c0.v[i] = L.y; c1.v[i] = L.z; c2.v[i] = L.w;
            c3.v[i] = C.x; c4.v[i] = C.y; c5.v[i] = C.z; c6.v[i] = C.w;
            c7.v[i] = R.x; c8.v[i] = R.y; c9.v[i] = R.z;
        }
    } else if (x0 == 0) {
        // left border: window cols -3..6 reflect to {3,2,1,0,1,2,3,4,5,6}
        // = static wiring of cols[0..7] (2 aligned float4 per row).
#pragma unroll
        for (int i = 0; i < 7; ++i) {
            const float* rp = img + rows[i];
            float4 A = *reinterpret_cast<const float4*>(rp);      // cols 0..3
            float4 B = *reinterpret_cast<const float4*>(rp + 4);  // cols 4..7
            c0.v[i] = A.w; c1.v[i] = A.z; c2.v[i] = A.y;
            c3.v[i] = A.x; c4.v[i] = A.y; c5.v[i] = A.z; c6.v[i] = A.w;
            c7.v[i] = B.x; c8.v[i] = B.y; c9.v[i] = B.z;
        }
    } else {
        // right border (x0 == 508): window cols 505..514 reflect to
        // {505,506,507,508,509,510,511,510,509,508} = static wiring of
        // cols[504..511] (2 aligned float4 per row).
#pragma unroll
        for (int i = 0; i < 7; ++i) {
            const float* rp = img + rows[i];
            float4 A = *reinterpret_cast<const float4*>(rp + 504);  // 504..507
            float4 B = *reinterpret_cast<const float4*>(rp + 508);  // 508..511
            c0.v[i] = A.y; c1.v[i] = A.z; c2.v[i] = A.w;
            c3.v[i] = B.x; c4.v[i] = B.y; c5.v[i] = B.z; c6.v[i] = B.w;
            c7.v[i] = B.z; c8.v[i] = B.y; c9.v[i] = B.x;
        }
    }

    c0 = sort7(c0); c1 = sort7(c1); c2 = sort7(c2); c3 = sort7(c3);
    c4 = sort7(c4); c5 = sort7(c5); c6 = sort7(c6); c7 = sort7(c7);
    c8 = sort7(c8); c9 = sort7(c9);

    V<28> Q = mrg<14, 14>(mrg<7, 7>(c3, c4), mrg<7, 7>(c5, c6));

    V<42> QP12 = mrg<28, 14>(Q, mrg<7, 7>(c1, c2));
    float m0 = sel8(QP12, c0);
    float m1 = sel8(QP12, c7);

    V<42> QP78 = mrg<28, 14>(Q, mrg<7, 7>(c7, c8));
    float m2 = sel8(QP78, c2);
    float m3 = sel8(QP78, c9);

    float4 o;
    o.x = __builtin_amdgcn_fmed3f(m0, 0.0f, 1.0f);  // hardtanh = clamp
    o.y = __builtin_amdgcn_fmed3f(m1, 0.0f, 1.0f);
    o.z = __builtin_amdgcn_fmed3f(m2, 0.0f, 1.0f);
    o.w = __builtin_amdgcn_fmed3f(m3, 0.0f, 1.0f);
    *reinterpret_cast<float4*>(out + (size_t)r * W + x0) = o;
}

extern "C" void kernel_launch(void* const* d_in, const int* in_sizes, int n_in,
                              void* d_out, int out_size, void* d_ws, size_t ws_size,
                              hipStream_t stream) {
    const float* x = (const float*)d_in[0];
    float* outp = (float*)d_out;
    int rows_total = out_size / W;      // 12288
    int blocks = rows_total / 2;        // 6144
    median7_hardtanh_kernel<<<blocks, 256, 0, stream>>>(x, outp);
}